// Round 1
// baseline (123.585 us; speedup 1.0000x reference)
//
#include <hip/hip_runtime.h>
#include <hip/hip_bf16.h>

#define BB 64
#define SS 512
#define TT 32
#define MID 256
#define ENDI 31
#define NEGBIG (-1e30f)

// lse over 32 values: 16 held per lane (v[0..15]), other 16 in the partner
// half-wave (lane ^ 32). Returns full 32-element logsumexp, replicated.
__device__ __forceinline__ float lse32_cross(float v[16]) {
  float m[8];
#pragma unroll
  for (int j = 0; j < 8; ++j) m[j] = fmaxf(v[2 * j], v[2 * j + 1]);
#pragma unroll
  for (int j = 0; j < 4; ++j) m[j] = fmaxf(m[2 * j], m[2 * j + 1]);
  float mp = fmaxf(fmaxf(m[0], m[1]), fmaxf(m[2], m[3]));
  mp = fmaxf(mp, __shfl_xor(mp, 32));
  float e[8];
#pragma unroll
  for (int j = 0; j < 8; ++j)
    e[j] = __expf(v[2 * j] - mp) + __expf(v[2 * j + 1] - mp);
#pragma unroll
  for (int j = 0; j < 4; ++j) e[j] = e[2 * j] + e[2 * j + 1];
  float sp = (e[0] + e[1]) + (e[2] + e[3]);
  sp += __shfl_xor(sp, 32);
  return mp + __logf(sp);
}

// Gold score: sum over (b,s) with s < len[b] of scores.flat[targets[b,s]].
__global__ __launch_bounds__(256) void gold_kernel(
    const float* __restrict__ scores, const int* __restrict__ targets,
    const int* __restrict__ lengths, float* __restrict__ ws) {
  int idx = blockIdx.x * 256 + threadIdx.x;  // exactly B*S threads
  int b = idx >> 9;
  int s = idx & (SS - 1);
  float val = 0.f;
  if (s < lengths[b]) {
    val = scores[(size_t)idx * (TT * TT) + (size_t)targets[idx]];
  }
#pragma unroll
  for (int o = 32; o; o >>= 1) val += __shfl_xor(val, o);
  if ((threadIdx.x & 63) == 0) atomicAdd(ws, val);
}

// One wave64 per (batch, direction). Forward: fs over s in [0, min(MID,len)).
// Backward: row vector r = e_END^T * M_{len-1}...M_{MID} (log-semiring).
// Lane layout: lo = lane & 31 owns one state index; h = lane>>5 covers half
// of the 32-wide reduction axis (16 values per lane).
__global__ __launch_bounds__(64) void crf_fb_kernel(
    const float* __restrict__ sc, const int* __restrict__ lengths,
    float* __restrict__ ws) {
  const int bid = blockIdx.x;
  const int b = bid & (BB - 1);
  const bool bwd = bid >= BB;
  const int l = threadIdx.x;
  const int lo = l & 31;
  const int h = l >> 5;
  const int len = lengths[b];
  __shared__ alignas(16) float st[TT];
  float* wout = ws + 64 + b * 64 + (bwd ? 32 : 0);
  const float* base = sc + (size_t)b * SS * (TT * TT);

  if (!bwd) {
    // ---- forward: fs'[cur] = lse_prev(sc[s,cur,prev] + fs[prev]) ----
    float v[16];
    {
      const float4* p = (const float4*)(base + lo * TT + h * 16);
      float4 a0 = p[0], a1 = p[1], a2 = p[2], a3 = p[3];
      v[0] = a0.x; v[1] = a0.y; v[2] = a0.z; v[3] = a0.w;
      v[4] = a1.x; v[5] = a1.y; v[6] = a1.z; v[7] = a1.w;
      v[8] = a2.x; v[9] = a2.y; v[10] = a2.z; v[11] = a2.w;
      v[12] = a3.x; v[13] = a3.y; v[14] = a3.z; v[15] = a3.w;
    }
    float f = lse32_cross(v);  // fs0[lo]
    if (h == 0) st[lo] = f;
    __syncthreads();
    const int send = (len < MID) ? len : MID;
    // prefetch s=1 (always in-bounds; loop may not run)
    float4 c0, c1, c2, c3;
    {
      const float4* p = (const float4*)(base + 1024 + lo * TT + h * 16);
      c0 = p[0]; c1 = p[1]; c2 = p[2]; c3 = p[3];
    }
    for (int s = 1; s < send; ++s) {
      float4 u0 = c0, u1 = c1, u2 = c2, u3 = c3;
      {  // prefetch s+1 (s+1 <= MID < SS, always in-bounds)
        const float4* p =
            (const float4*)(base + (size_t)(s + 1) * 1024 + lo * TT + h * 16);
        c0 = p[0]; c1 = p[1]; c2 = p[2]; c3 = p[3];
      }
      const float4* g4 = (const float4*)st;
      float4 g0 = g4[h * 4 + 0], g1 = g4[h * 4 + 1], g2 = g4[h * 4 + 2],
             g3 = g4[h * 4 + 3];
      v[0] = u0.x + g0.x; v[1] = u0.y + g0.y; v[2] = u0.z + g0.z; v[3] = u0.w + g0.w;
      v[4] = u1.x + g1.x; v[5] = u1.y + g1.y; v[6] = u1.z + g1.z; v[7] = u1.w + g1.w;
      v[8] = u2.x + g2.x; v[9] = u2.y + g2.y; v[10] = u2.z + g2.z; v[11] = u2.w + g2.w;
      v[12] = u3.x + g3.x; v[13] = u3.y + g3.y; v[14] = u3.z + g3.z; v[15] = u3.w + g3.w;
      f = lse32_cross(v);
      __syncthreads();
      if (h == 0) st[lo] = f;
      __syncthreads();
    }
    if (h == 0) wout[lo] = f;
  } else {
    // ---- backward row recurrence: r'[p] = lse_c(r[c] + sc[s,c,p]) ----
    float f = (lo == ENDI) ? 0.f : NEGBIG;  // r[lo]
    if (h == 0) st[lo] = f;
    __syncthreads();
    const int sstart = len - 1;
    float cn[16];
    if (sstart >= MID) {
      const float* p = base + (size_t)sstart * 1024 + (h * 16) * TT + lo;
#pragma unroll
      for (int j = 0; j < 16; ++j) cn[j] = p[j * TT];
    }
    for (int s = sstart; s >= MID; --s) {
      float u[16];
#pragma unroll
      for (int j = 0; j < 16; ++j) u[j] = cn[j];
      {  // prefetch s-1 (s-1 >= MID-1 >= 0, in-bounds)
        const float* p = base + (size_t)(s - 1) * 1024 + (h * 16) * TT + lo;
#pragma unroll
        for (int j = 0; j < 16; ++j) cn[j] = p[j * TT];
      }
      float v[16];
#pragma unroll
      for (int j = 0; j < 16; ++j) v[j] = u[j] + st[h * 16 + j];
      f = lse32_cross(v);
      __syncthreads();
      if (h == 0) st[lo] = f;
      __syncthreads();
    }
    if (h == 0) wout[lo] = f;
  }
}

// Combine: per batch, lse_p(fs_mid[p] + r_mid[p]); sum over batches; subtract
// gold.
__global__ __launch_bounds__(64) void crf_fin_kernel(
    const float* __restrict__ ws, float* __restrict__ out) {
  int b = threadIdx.x;  // 64 lanes = 64 batches
  const float* f = ws + 64 + b * 64;
  float w[32];
#pragma unroll
  for (int j = 0; j < 32; ++j) w[j] = f[j] + f[32 + j];
  float mp = w[0];
#pragma unroll
  for (int j = 1; j < 32; ++j) mp = fmaxf(mp, w[j]);
  float sp = 0.f;
#pragma unroll
  for (int j = 0; j < 32; ++j) sp += __expf(w[j] - mp);
  float r = mp + __logf(sp);
#pragma unroll
  for (int o = 32; o; o >>= 1) r += __shfl_xor(r, o);
  if (b == 0) out[0] = r - ws[0];
}

extern "C" void kernel_launch(void* const* d_in, const int* in_sizes, int n_in,
                              void* d_out, int out_size, void* d_ws,
                              size_t ws_size, hipStream_t stream) {
  const float* scores = (const float*)d_in[0];
  const int* targets = (const int*)d_in[1];
  const int* lengths = (const int*)d_in[2];
  float* out = (float*)d_out;
  float* ws = (float*)d_ws;

  // zero the gold accumulator (ws[0]); everything else is fully overwritten
  hipMemsetAsync(d_ws, 0, sizeof(float), stream);

  gold_kernel<<<(BB * SS) / 256, 256, 0, stream>>>(scores, targets, lengths,
                                                   ws);
  crf_fb_kernel<<<2 * BB, 64, 0, stream>>>(scores, lengths, ws);
  crf_fin_kernel<<<1, 64, 0, stream>>>(ws, out);
}

// Round 2
// 113.142 us; speedup vs baseline: 1.0923x; 1.0923x over previous
//
#include <hip/hip_runtime.h>
#include <hip/hip_bf16.h>

#define BB 64
#define SS 512
#define TT 32
#define MID 256
#define ENDI 31

// ---------------------------------------------------------------------------
// Gold score: sum over (b,s) with s < len[b] of scores.flat[targets[b,s]].
__global__ __launch_bounds__(256) void gold_kernel(
    const float* __restrict__ scores, const int* __restrict__ targets,
    const int* __restrict__ lengths, float* __restrict__ ws) {
  int idx = blockIdx.x * 256 + threadIdx.x;  // exactly B*S threads
  int b = idx >> 9;
  int s = idx & (SS - 1);
  float val = 0.f;
  if (s < lengths[b]) {
    val = scores[(size_t)idx * (TT * TT) + (size_t)targets[idx]];
  }
#pragma unroll
  for (int o = 32; o; o >>= 1) val += __shfl_xor(val, o);
  if ((threadIdx.x & 63) == 0) atomicAdd(ws, val);
}

// ---------------------------------------------------------------------------
// One wave64 per (batch, direction). Exp-domain recurrence:
//   fwd: G'[c] = sum_p E[s,c,p] * G[p]    (E = exp(scores))
//   bwd: G'[p] = sum_c G[c] * E[s,c,p]
// with exact power-of-2 rescaling each step (esum accumulates the exponent).
// True log-domain state = esum*ln2 + log(G[.]).
// Lane layout: lo = lane&31 owns output index; h = lane>>5 covers half of the
// 32-wide reduction axis (16 E values + 16 G values per lane).
__global__ __launch_bounds__(64) void crf_fb_kernel(
    const float* __restrict__ sc, const int* __restrict__ lengths,
    float* __restrict__ ws) {
  const int bid = blockIdx.x;
  const int b = bid & (BB - 1);
  const bool bwd = bid >= BB;
  const int l = threadIdx.x;
  const int lo = l & 31;
  const int h = l >> 5;
  const int len = lengths[b];
  __shared__ alignas(16) float st[TT];
  float* wout = ws + 64 + b * 66;
  const float* base = sc + (size_t)b * SS * (TT * TT);

  float e[16];
  float A[16], Bu[16], C[16];
  float cur = 0.f;
  int esum = 0;

// Single wave per block: an lgkmcnt drain replaces __syncthreads().
#define FENCE() asm volatile("s_waitcnt lgkmcnt(0)" ::: "memory")

// Row load (fwd): 16 consecutive floats of row c=lo, cols h*16..h*16+15.
#define LOADF(buf, S)                                                        \
  do {                                                                       \
    const float4* _p =                                                       \
        (const float4*)(base + (size_t)(S) * 1024 + lo * 32 + h * 16);       \
    float4 _t0 = _p[0], _t1 = _p[1], _t2 = _p[2], _t3 = _p[3];               \
    buf[0] = _t0.x;  buf[1] = _t0.y;  buf[2] = _t0.z;  buf[3] = _t0.w;       \
    buf[4] = _t1.x;  buf[5] = _t1.y;  buf[6] = _t1.z;  buf[7] = _t1.w;       \
    buf[8] = _t2.x;  buf[9] = _t2.y;  buf[10] = _t2.z; buf[11] = _t2.w;      \
    buf[12] = _t3.x; buf[13] = _t3.y; buf[14] = _t3.z; buf[15] = _t3.w;      \
  } while (0)

// Column load (bwd): E[c, lo] for c = h*16+j (stride-32 floats, coalesced
// 128B per j across the 32 lo-lanes).
#define LOADB(buf, S)                                                        \
  do {                                                                       \
    const float* _p = base + (size_t)(S) * 1024 + (h * 16) * 32 + lo;        \
    _Pragma("unroll") for (int _j = 0; _j < 16; ++_j) buf[_j] = _p[_j * 32]; \
  } while (0)

#define EXPV(dst, buf)                                              \
  do {                                                              \
    _Pragma("unroll") for (int _j = 0; _j < 16; ++_j) dst[_j] =     \
        __expf(buf[_j]);                                            \
  } while (0)

// One recurrence step: read G from LDS, dot with e[], exact pow2 rescale,
// write back. Critical path: ds_read -> fma tree -> shfl -> mul -> ds_write.
#define STEP()                                                               \
  do {                                                                       \
    const float4* _s4 = (const float4*)st;                                   \
    float4 _g0 = _s4[h * 4 + 0], _g1 = _s4[h * 4 + 1],                       \
           _g2 = _s4[h * 4 + 2], _g3 = _s4[h * 4 + 3];                       \
    float _g[16] = {_g0.x, _g0.y, _g0.z, _g0.w, _g1.x, _g1.y, _g1.z, _g1.w,  \
                    _g2.x, _g2.y, _g2.z, _g2.w, _g3.x, _g3.y, _g3.z, _g3.w}; \
    float _m[8];                                                             \
    _Pragma("unroll") for (int _j = 0; _j < 8; ++_j) _m[_j] =                \
        fmaxf(_g[2 * _j], _g[2 * _j + 1]);                                   \
    _Pragma("unroll") for (int _j = 0; _j < 4; ++_j) _m[_j] =                \
        fmaxf(_m[2 * _j], _m[2 * _j + 1]);                                   \
    float _ml = fmaxf(fmaxf(_m[0], _m[1]), fmaxf(_m[2], _m[3]));             \
    float _ma = fmaxf(_ml, __shfl_xor(_ml, 32));                             \
    int _ex = ((__float_as_int(_ma) >> 23) & 255) - 127;                     \
    float _sc2 = __int_as_float((127 - _ex) << 23);                          \
    float _acc[4];                                                           \
    _Pragma("unroll") for (int _k = 0; _k < 4; ++_k) {                       \
      _acc[_k] = e[4 * _k] * _g[4 * _k];                                     \
      _Pragma("unroll") for (int _t = 1; _t < 4; ++_t) _acc[_k] =            \
          fmaf(e[4 * _k + _t], _g[4 * _k + _t], _acc[_k]);                   \
    }                                                                        \
    float _part = (_acc[0] + _acc[1]) + (_acc[2] + _acc[3]);                 \
    float _dot = _part + __shfl_xor(_part, 32);                              \
    cur = _dot * _sc2;                                                       \
    esum += _ex;                                                             \
    st[lo] = cur;                                                            \
    FENCE();                                                                 \
  } while (0)

  if (!bwd) {
    // init: G0[c] = sum_p exp(sc[0,c,p]); esum = 0 (no rescale needed yet)
    LOADF(A, 0);
    EXPV(e, A);
    {
      float p0 = (e[0] + e[1]) + (e[2] + e[3]);
      float p1 = (e[4] + e[5]) + (e[6] + e[7]);
      float p2 = (e[8] + e[9]) + (e[10] + e[11]);
      float p3 = (e[12] + e[13]) + (e[14] + e[15]);
      float part = (p0 + p1) + (p2 + p3);
      cur = part + __shfl_xor(part, 32);
    }
    st[lo] = cur;
    FENCE();
    const int send = (len < MID) ? len : MID;
    int rem = send - 1;
    int s = 1;
    if (rem > 0) {
      LOADF(A, 1);
      LOADF(Bu, 2);
      LOADF(C, 3);
      EXPV(e, A);
      while (rem >= 3) {
        STEP();  // row s
        EXPV(e, Bu);
        LOADF(A, s + 3);
        STEP();  // row s+1
        EXPV(e, C);
        LOADF(Bu, s + 4);
        STEP();  // row s+2
        EXPV(e, A);
        LOADF(C, s + 5);
        s += 3;
        rem -= 3;
      }
      for (; rem > 0; --rem, ++s) {  // <=2 leftover steps, direct loads
        LOADF(A, s);
        EXPV(e, A);
        STEP();
      }
    }
    if (h == 0) wout[lo] = cur;
    if (l == 0) wout[64] = (float)esum;
  } else {
    // init: r = e_END in exp domain
    cur = (lo == ENDI) ? 1.0f : 0.0f;
    st[lo] = cur;
    FENCE();
    const int sstart = len - 1;
    int rem = (sstart >= MID) ? (sstart - MID + 1) : 0;
    int s = sstart;
    if (rem > 0) {
      LOADB(A, s);
      LOADB(Bu, s - 1);
      LOADB(C, s - 2);
      EXPV(e, A);
      while (rem >= 3) {
        STEP();  // row s
        EXPV(e, Bu);
        LOADB(A, s - 3);
        STEP();  // row s-1
        EXPV(e, C);
        LOADB(Bu, s - 4);
        STEP();  // row s-2
        EXPV(e, A);
        LOADB(C, s - 5);
        s -= 3;
        rem -= 3;
      }
      for (; rem > 0; --rem, --s) {
        LOADB(A, s);
        EXPV(e, A);
        STEP();
      }
    }
    if (h == 0) wout[32 + lo] = cur;
    if (l == 0) wout[65] = (float)esum;
  }
#undef STEP
#undef EXPV
#undef LOADB
#undef LOADF
#undef FENCE
}

// ---------------------------------------------------------------------------
// Combine: per batch, total_b = (esum_f+esum_b)*ln2 + log(sum_p Gf[p]*Gr[p]);
// out = sum_b total_b - gold.
__global__ __launch_bounds__(64) void crf_fin_kernel(
    const float* __restrict__ ws, float* __restrict__ out) {
  int b = threadIdx.x;  // 64 lanes = 64 batches
  const float* f = ws + 64 + b * 66;
  float dot = 0.f;
#pragma unroll
  for (int j = 0; j < 32; ++j) dot = fmaf(f[j], f[32 + j], dot);
  float r = (f[64] + f[65]) * 0.6931471805599453f + __logf(dot);
#pragma unroll
  for (int o = 32; o; o >>= 1) r += __shfl_xor(r, o);
  if (b == 0) out[0] = r - ws[0];
}

extern "C" void kernel_launch(void* const* d_in, const int* in_sizes, int n_in,
                              void* d_out, int out_size, void* d_ws,
                              size_t ws_size, hipStream_t stream) {
  const float* scores = (const float*)d_in[0];
  const int* targets = (const int*)d_in[1];
  const int* lengths = (const int*)d_in[2];
  float* out = (float*)d_out;
  float* ws = (float*)d_ws;

  // zero the gold accumulator (ws[0]); everything else is fully overwritten
  hipMemsetAsync(d_ws, 0, sizeof(float), stream);

  gold_kernel<<<(BB * SS) / 256, 256, 0, stream>>>(scores, targets, lengths,
                                                   ws);
  crf_fb_kernel<<<2 * BB, 64, 0, stream>>>(scores, lengths, ws);
  crf_fin_kernel<<<1, 64, 0, stream>>>(ws, out);
}

// Round 3
// 68.791 us; speedup vs baseline: 1.7965x; 1.6447x over previous
//
#include <hip/hip_runtime.h>
#include <hip/hip_bf16.h>

#define BB 64
#define SS 512
#define TT 32
#define ENDI 31

typedef __attribute__((ext_vector_type(8))) short s8v;    // 8 bf16 (4 VGPR)
typedef __attribute__((ext_vector_type(16))) float fx16;  // MFMA accumulator

union S8U {
  s8v v;
  unsigned int u[4];
};

__device__ __forceinline__ unsigned int cvtpk_bf16(float a, float b) {
  unsigned int r;
  asm("v_cvt_pk_bf16_f32 %0, %1, %2" : "=v"(r) : "v"(a), "v"(b));
  return r;
}

// ---------------------------------------------------------------------------
// Gold score: sum over (b,s) with s < len[b] of scores.flat[targets[b,s]].
__global__ __launch_bounds__(256) void gold_kernel(
    const float* __restrict__ scores, const int* __restrict__ targets,
    const int* __restrict__ lengths, float* __restrict__ ws) {
  int idx = blockIdx.x * 256 + threadIdx.x;  // exactly B*S threads
  int b = idx >> 9;
  int s = idx & (SS - 1);
  float val = 0.f;
  if (s < lengths[b]) {
    val = scores[(size_t)idx * (TT * TT) + (size_t)targets[idx]];
  }
#pragma unroll
  for (int o = 32; o; o >>= 1) val += __shfl_xor(val, o);
  if ((threadIdx.x & 63) == 0) atomicAdd(ws, val);
}

// ---------------------------------------------------------------------------
// Stage 1: one wave per (batch, segment). Computes the exp-domain segment
// product P_seg = E_{hi-1} ... E_{lo}  (E_s = exp(scores[b,s]), identity for
// s >= len) as a 32x32 f32 matrix (normalized so max in [1,2)) + esum.
//
// MFMA layouts (v_mfma_f32_32x32x16_bf16), c = lane&31, h = lane>>5:
//   A slot j (chunk q): A[row=c][k = 16q + 8h + j]
//   B slot j (chunk q): B[k = 16q + 8h + j][col=c]
//   D reg r:            D[row = (r&3) + 8*(r>>2) + 4h][col=c]   (HW-verified)
// Any consistent misassumption about the A/B k-slot map cancels (same perm
// applied to both operands of the contraction).
__global__ __launch_bounds__(64) void seg_kernel(
    const float* __restrict__ sc, const int* __restrict__ lengths,
    float* __restrict__ ws, int nseg, int seglen) {
  const int b = blockIdx.x;
  const int seg = blockIdx.y;
  const int l = threadIdx.x;
  const int c = l & 31;
  const int h = l >> 5;
  const int len = lengths[b];
  const int lo = seg * seglen;
  float* mout = ws + 16 + (size_t)(b * nseg + seg) * 1056;

  if (len <= lo) {  // segment fully past the sequence: identity
#pragma unroll
    for (int r = 0; r < 16; ++r) {
      int row = (r & 3) + 8 * (r >> 2) + 4 * h;
      mout[row * 32 + c] = (row == c) ? 1.0f : 0.0f;
    }
    if (l == 0) mout[1024] = 0.0f;
    return;
  }

  const int hi = (lo + seglen < len) ? (lo + seglen) : len;
  const int nsteps = hi - lo;
  const float* base = sc + ((size_t)b * SS + lo) * 1024;

  // B state = identity (bf16 1.0 = 0x3F80 at m == c)
  S8U B0, B1;
#pragma unroll
  for (int q = 0; q < 4; ++q) {
    B0.u[q] = 0u;
    B1.u[q] = 0u;
  }
  {
    int j0 = c - 8 * h;  // chunk0 holds m = 8h+j
    if (j0 >= 0 && j0 < 8) B0.u[j0 >> 1] |= 0x3F80u << (16 * (j0 & 1));
    int j1 = c - 16 - 8 * h;  // chunk1 holds m = 16+8h+j
    if (j1 >= 0 && j1 < 8) B1.u[j1 >> 1] |= 0x3F80u << (16 * (j1 & 1));
  }

// Load E-row raw scores for step T: lane (c,h) takes cols [8h,8h+8) and
// [16+8h,16+8h+8) of row c.
#define LOADE(buf, T)                                                     \
  do {                                                                    \
    const float* _p = base + (size_t)(T) * 1024 + c * 32 + 8 * h;         \
    float4 _a = *(const float4*)_p;                                       \
    float4 _b = *(const float4*)(_p + 4);                                 \
    float4 _c = *(const float4*)(_p + 16);                                \
    float4 _d = *(const float4*)(_p + 20);                                \
    buf[0] = _a.x;  buf[1] = _a.y;  buf[2] = _a.z;  buf[3] = _a.w;        \
    buf[4] = _b.x;  buf[5] = _b.y;  buf[6] = _b.z;  buf[7] = _b.w;        \
    buf[8] = _c.x;  buf[9] = _c.y;  buf[10] = _c.z; buf[11] = _c.w;       \
    buf[12] = _d.x; buf[13] = _d.y; buf[14] = _d.z; buf[15] = _d.w;       \
  } while (0)

  float raw[16], rawn[16];
  LOADE(raw, 0);
  int esum = 0;
  fx16 C;
#pragma unroll
  for (int q = 0; q < 16; ++q) C[q] = 0.f;

  for (int t = 0; t < nsteps; ++t) {
    // A = exp(raw) packed to bf16
    S8U A0, A1;
#pragma unroll
    for (int q = 0; q < 4; ++q) {
      A0.u[q] = cvtpk_bf16(__expf(raw[2 * q]), __expf(raw[2 * q + 1]));
      A1.u[q] = cvtpk_bf16(__expf(raw[8 + 2 * q]), __expf(raw[9 + 2 * q]));
    }
    // prefetch next step's scores
    int nidx = (t + 1 < nsteps) ? (t + 1) : 0;
    LOADE(rawn, nidx);

    fx16 Cl;
#pragma unroll
    for (int q = 0; q < 16; ++q) Cl[q] = 0.f;
    Cl = __builtin_amdgcn_mfma_f32_32x32x16_bf16(A0.v, B0.v, Cl, 0, 0, 0);
    Cl = __builtin_amdgcn_mfma_f32_32x32x16_bf16(A1.v, B1.v, Cl, 0, 0, 0);

    if (t + 1 < nsteps) {
      float s = 1.0f;
      if ((t & 3) == 3) {  // wave-uniform power-of-2 rescale
        float mx = Cl[0];
#pragma unroll
        for (int q = 1; q < 16; ++q) mx = fmaxf(mx, Cl[q]);
        mx = fmaxf(mx, __shfl_xor(mx, 32));
        mx = fmaxf(mx, __shfl_xor(mx, 1));
        mx = fmaxf(mx, __shfl_xor(mx, 2));
        mx = fmaxf(mx, __shfl_xor(mx, 4));
        mx = fmaxf(mx, __shfl_xor(mx, 8));
        mx = fmaxf(mx, __shfl_xor(mx, 16));
        int ex = ((__float_as_int(mx) >> 23) & 255) - 127;
        s = __int_as_float((unsigned)(127 - ex) << 23);  // 2^-ex
        esum += ex;
      }
      // D -> B operand for next step (rows redistribute within lane pairs)
      unsigned int W[8], X[8];
#pragma unroll
      for (int q = 0; q < 8; ++q)
        W[q] = cvtpk_bf16(Cl[2 * q] * s, Cl[2 * q + 1] * s);
#pragma unroll
      for (int q = 0; q < 8; ++q) X[q] = __shfl_xor((int)W[q], 32);
      B0.u[0] = h ? X[2] : W[0];
      B0.u[1] = h ? X[3] : W[1];
      B0.u[2] = h ? W[2] : X[0];
      B0.u[3] = h ? W[3] : X[1];
      B1.u[0] = h ? X[6] : W[4];
      B1.u[1] = h ? X[7] : W[5];
      B1.u[2] = h ? W[6] : X[4];
      B1.u[3] = h ? W[7] : X[5];
    } else {
      C = Cl;
    }
#pragma unroll
    for (int q = 0; q < 16; ++q) raw[q] = rawn[q];
  }

  // final normalize (max into [1,2)) and store f32 matrix + esum
  float mx = C[0];
#pragma unroll
  for (int q = 1; q < 16; ++q) mx = fmaxf(mx, C[q]);
  mx = fmaxf(mx, __shfl_xor(mx, 32));
  mx = fmaxf(mx, __shfl_xor(mx, 1));
  mx = fmaxf(mx, __shfl_xor(mx, 2));
  mx = fmaxf(mx, __shfl_xor(mx, 4));
  mx = fmaxf(mx, __shfl_xor(mx, 8));
  mx = fmaxf(mx, __shfl_xor(mx, 16));
  int ex = ((__float_as_int(mx) >> 23) & 255) - 127;
  float s = __int_as_float((unsigned)(127 - ex) << 23);
  esum += ex;
#pragma unroll
  for (int r = 0; r < 16; ++r) {
    int row = (r & 3) + 8 * (r >> 2) + 4 * h;
    mout[row * 32 + c] = C[r] * s;
  }
  if (l == 0) mout[1024] = (float)esum;
#undef LOADE
}

// ---------------------------------------------------------------------------
// Stage 2: one wave per (batch, direction). dir0: v <- M_seg * v for
// seg = 0..half-1 starting v = ones. dir1: r <- r * M_seg for
// seg = nseg-1 .. half. No rescaling needed (matrices normalized; <=2^6
// growth per step over <=8 steps). Accumulates stored esums.
__global__ __launch_bounds__(64) void comb_kernel(float* __restrict__ ws,
                                                  int nseg) {
  const int bid = blockIdx.x;
  const int b = bid & (BB - 1);
  const int dir = bid >> 6;
  const int l = threadIdx.x;
  const int lo = l & 31;
  const int h = l >> 5;
  const int half = nseg >> 1;
  __shared__ alignas(16) float st[TT];

#define FENCE() asm volatile("s_waitcnt lgkmcnt(0)" ::: "memory")

  float cur = dir ? ((lo == ENDI) ? 1.0f : 0.0f) : 1.0f;
  st[lo] = cur;
  FENCE();

  const float* segbase = ws + 16;
  float esv = 0.f;

#define LOADM(buf, SEG)                                                     \
  do {                                                                      \
    const float* _m = segbase + (size_t)(b * nseg + (SEG)) * 1056;          \
    if (dir == 0) { /* need M[lo][h16+j]: contiguous */                     \
      const float4* _p = (const float4*)(_m + lo * 32 + h * 16);            \
      float4 _a = _p[0], _b2 = _p[1], _c2 = _p[2], _d = _p[3];              \
      buf[0] = _a.x;  buf[1] = _a.y;  buf[2] = _a.z;  buf[3] = _a.w;        \
      buf[4] = _b2.x; buf[5] = _b2.y; buf[6] = _b2.z; buf[7] = _b2.w;       \
      buf[8] = _c2.x; buf[9] = _c2.y; buf[10] = _c2.z; buf[11] = _c2.w;     \
      buf[12] = _d.x; buf[13] = _d.y; buf[14] = _d.z; buf[15] = _d.w;       \
    } else { /* need M[h16+j][lo]: stride 32 */                             \
      const float* _p = _m + (h * 16) * 32 + lo;                            \
      _Pragma("unroll") for (int _j = 0; _j < 16; ++_j)                     \
          buf[_j] = _p[_j * 32];                                            \
    }                                                                       \
  } while (0)

  float mc[16], mn[16];
  {
    int seg0 = dir ? (nseg - 1) : 0;
    LOADM(mc, seg0);
  }
  for (int k = 0; k < half; ++k) {
    int segn = dir ? (nseg - 2 - k) : (k + 1);
    if (k + 1 < half) LOADM(mn, segn);
    int segc = dir ? (nseg - 1 - k) : k;
    esv += segbase[(size_t)(b * nseg + segc) * 1056 + 1024];
    const float4* g4 = (const float4*)st;
    float4 g0 = g4[h * 4 + 0], g1 = g4[h * 4 + 1], g2 = g4[h * 4 + 2],
           g3 = g4[h * 4 + 3];
    float g[16] = {g0.x, g0.y, g0.z, g0.w, g1.x, g1.y, g1.z, g1.w,
                   g2.x, g2.y, g2.z, g2.w, g3.x, g3.y, g3.z, g3.w};
    float acc[4];
#pragma unroll
    for (int q = 0; q < 4; ++q) {
      acc[q] = mc[4 * q] * g[4 * q];
#pragma unroll
      for (int t = 1; t < 4; ++t)
        acc[q] = fmaf(mc[4 * q + t], g[4 * q + t], acc[q]);
    }
    float part = (acc[0] + acc[1]) + (acc[2] + acc[3]);
    cur = part + __shfl_xor(part, 32);
    FENCE();  // all lanes done reading st before overwrite
    st[lo] = cur;
    FENCE();
#pragma unroll
    for (int q = 0; q < 16; ++q) mc[q] = mn[q];
  }

  float* o = ws + 16 + (size_t)BB * nseg * 1056 + (size_t)(b * 2 + dir) * 40;
  if (h == 0) o[lo] = cur;
  if (l == 0) o[32] = esv;
#undef LOADM
#undef FENCE
}

// ---------------------------------------------------------------------------
// Final: per batch, loss_b = (esumF+esumB)*ln2 + log(dot(vF, rB)); sum over
// batches, subtract gold.
__global__ __launch_bounds__(64) void fin_kernel(const float* __restrict__ ws,
                                                 int nseg,
                                                 float* __restrict__ out) {
  int b = threadIdx.x;  // 64 lanes = 64 batches
  const float* cb = ws + 16 + (size_t)BB * nseg * 1056;
  const float* vF = cb + (size_t)(b * 2) * 40;
  const float* rB = vF + 40;
  float dot = 0.f;
#pragma unroll
  for (int j = 0; j < 32; ++j) dot = fmaf(vF[j], rB[j], dot);
  float r = (vF[32] + rB[32]) * 0.6931471805599453f + __logf(dot);
#pragma unroll
  for (int o = 32; o; o >>= 1) r += __shfl_xor(r, o);
  if (b == 0) out[0] = r - ws[0];
}

// ---------------------------------------------------------------------------
extern "C" void kernel_launch(void* const* d_in, const int* in_sizes, int n_in,
                              void* d_out, int out_size, void* d_ws,
                              size_t ws_size, hipStream_t stream) {
  const float* scores = (const float*)d_in[0];
  const int* targets = (const int*)d_in[1];
  const int* lengths = (const int*)d_in[2];
  float* out = (float*)d_out;
  float* ws = (float*)d_ws;

  // pick nseg to fit the workspace (matrices + combine outputs + gold slot)
  int nseg = 16;
  while (nseg > 2) {
    size_t need =
        (size_t)(16 + BB * nseg * 1056 + BB * 2 * 40) * sizeof(float);
    if (need <= ws_size) break;
    nseg >>= 1;
  }
  int seglen = SS / nseg;

  hipMemsetAsync(d_ws, 0, sizeof(float), stream);  // gold accumulator
  gold_kernel<<<(BB * SS) / 256, 256, 0, stream>>>(scores, targets, lengths,
                                                   ws);
  seg_kernel<<<dim3(BB, nseg), 64, 0, stream>>>(scores, lengths, ws, nseg,
                                                seglen);
  comb_kernel<<<2 * BB, 64, 0, stream>>>(ws, nseg);
  fin_kernel<<<1, 64, 0, stream>>>(ws, nseg, out);
}

// Round 5
// 57.460 us; speedup vs baseline: 2.1508x; 1.1972x over previous
//
#include <hip/hip_runtime.h>
#include <hip/hip_bf16.h>

#define BB 64
#define SS 512
#define TT 32
#define ENDI 31

typedef __attribute__((ext_vector_type(8))) short s8v;    // 8 bf16 (4 VGPR)
typedef __attribute__((ext_vector_type(16))) float fx16;  // MFMA accumulator

union S8U {
  s8v v;
  unsigned int u[4];
};

__device__ __forceinline__ unsigned int cvtpk_bf16(float a, float b) {
  unsigned int r;
  asm("v_cvt_pk_bf16_f32 %0, %1, %2" : "=v"(r) : "v"(a), "v"(b));
  return r;
}

// ---------------------------------------------------------------------------
// Gold: per-wave partial sums of scores.flat[targets[b,s]] for s < len[b].
// 128 blocks x 4 waves -> 512 partial slots in ws[0..512). No atomics, no
// pre-zeroing (every slot written unconditionally).
__global__ __launch_bounds__(256) void gold_kernel(
    const float* __restrict__ scores, const int* __restrict__ targets,
    const int* __restrict__ lengths, float* __restrict__ ws) {
  int idx = blockIdx.x * 256 + threadIdx.x;  // exactly B*S threads
  int b = idx >> 9;
  int s = idx & (SS - 1);
  float val = 0.f;
  if (s < lengths[b]) {
    val = scores[(size_t)idx * (TT * TT) + (size_t)targets[idx]];
  }
#pragma unroll
  for (int o = 32; o; o >>= 1) val += __shfl_xor(val, o);
  if ((threadIdx.x & 63) == 0)
    ws[blockIdx.x * 4 + (threadIdx.x >> 6)] = val;
}

// ---------------------------------------------------------------------------
// Stage 1: one wave per (batch, segment). Computes the exp-domain segment
// product P_seg = E_{hi-1} ... E_{lo}  (E_s = exp(scores[b,s]), identity for
// s >= len) as a 32x32 f32 matrix (normalized so max in [1,2)) + esum.
// Register-double-buffered raw-score prefetch, depth 2 (r0/r1, unroll 2).
//
// MFMA layouts (v_mfma_f32_32x32x16_bf16), c = lane&31, h = lane>>5:
//   A slot j (chunk q): A[row=c][k = 16q + 8h + j]
//   B slot j (chunk q): B[k = 16q + 8h + j][col=c]
//   D reg r:            D[row = (r&3) + 8*(r>>2) + 4h][col=c]   (HW-verified)
__global__ __launch_bounds__(64) void seg_kernel(
    const float* __restrict__ sc, const int* __restrict__ lengths,
    float* __restrict__ ws, int nseg, int seglen) {
  const int b = blockIdx.x;
  const int seg = blockIdx.y;
  const int l = threadIdx.x;
  const int c = l & 31;
  const int h = l >> 5;
  const int len = lengths[b];
  const int lo = seg * seglen;
  float* mout = ws + 512 + (size_t)(b * nseg + seg) * 1056;

  if (len <= lo) {  // segment fully past the sequence: identity
#pragma unroll
    for (int r = 0; r < 16; ++r) {
      int row = (r & 3) + 8 * (r >> 2) + 4 * h;
      mout[row * 32 + c] = (row == c) ? 1.0f : 0.0f;
    }
    if (l == 0) mout[1024] = 0.0f;
    return;
  }

  const int hi = (lo + seglen < len) ? (lo + seglen) : len;
  const int nsteps = hi - lo;
  const float* base = sc + ((size_t)b * SS + lo) * 1024;

  // B state = identity (bf16 1.0 = 0x3F80 at m == c)
  S8U B0, B1;
#pragma unroll
  for (int q = 0; q < 4; ++q) {
    B0.u[q] = 0u;
    B1.u[q] = 0u;
  }
  {
    int j0 = c - 8 * h;  // chunk0 holds m = 8h+j
    if (j0 >= 0 && j0 < 8) B0.u[j0 >> 1] |= 0x3F80u << (16 * (j0 & 1));
    int j1 = c - 16 - 8 * h;  // chunk1 holds m = 16+8h+j
    if (j1 >= 0 && j1 < 8) B1.u[j1 >> 1] |= 0x3F80u << (16 * (j1 & 1));
  }

// Load E-row raw scores for step T: lane (c,h) takes cols [8h,8h+8) and
// [16+8h,16+8h+8) of row c.
#define LOADE(buf, T)                                                     \
  do {                                                                    \
    const float* _p = base + (size_t)(T) * 1024 + c * 32 + 8 * h;         \
    float4 _a = *(const float4*)_p;                                       \
    float4 _b = *(const float4*)(_p + 4);                                 \
    float4 _c = *(const float4*)(_p + 16);                                \
    float4 _d = *(const float4*)(_p + 20);                                \
    buf[0] = _a.x;  buf[1] = _a.y;  buf[2] = _a.z;  buf[3] = _a.w;        \
    buf[4] = _b.x;  buf[5] = _b.y;  buf[6] = _b.z;  buf[7] = _b.w;        \
    buf[8] = _c.x;  buf[9] = _c.y;  buf[10] = _c.z; buf[11] = _c.w;       \
    buf[12] = _d.x; buf[13] = _d.y; buf[14] = _d.z; buf[15] = _d.w;       \
  } while (0)

// One chain step consuming raw buffer RB; re-issues RB's load for step t+2
// (clamped; duplicate loads of an already-valid row are harmless).
#define STEPB(RB)                                                            \
  do {                                                                      \
    S8U A0, A1;                                                             \
    _Pragma("unroll") for (int q = 0; q < 4; ++q) {                         \
      A0.u[q] = cvtpk_bf16(__expf(RB[2 * q]), __expf(RB[2 * q + 1]));       \
      A1.u[q] = cvtpk_bf16(__expf(RB[8 + 2 * q]), __expf(RB[9 + 2 * q]));   \
    }                                                                       \
    int _pf = t + 2;                                                        \
    if (_pf >= nsteps) _pf = nsteps - 1;                                    \
    LOADE(RB, _pf);                                                         \
    fx16 Cl;                                                                \
    _Pragma("unroll") for (int q = 0; q < 16; ++q) Cl[q] = 0.f;             \
    Cl = __builtin_amdgcn_mfma_f32_32x32x16_bf16(A0.v, B0.v, Cl, 0, 0, 0);  \
    Cl = __builtin_amdgcn_mfma_f32_32x32x16_bf16(A1.v, B1.v, Cl, 0, 0, 0);  \
    if (t + 1 < nsteps) {                                                   \
      float _s = 1.0f;                                                      \
      if ((t & 3) == 3) { /* wave-uniform power-of-2 rescale */             \
        float _mx = Cl[0];                                                  \
        _Pragma("unroll") for (int q = 1; q < 16; ++q) _mx =                \
            fmaxf(_mx, Cl[q]);                                              \
        _mx = fmaxf(_mx, __shfl_xor(_mx, 32));                              \
        _mx = fmaxf(_mx, __shfl_xor(_mx, 1));                               \
        _mx = fmaxf(_mx, __shfl_xor(_mx, 2));                               \
        _mx = fmaxf(_mx, __shfl_xor(_mx, 4));                               \
        _mx = fmaxf(_mx, __shfl_xor(_mx, 8));                               \
        _mx = fmaxf(_mx, __shfl_xor(_mx, 16));                              \
        int _ex = ((__float_as_int(_mx) >> 23) & 255) - 127;                \
        _s = __int_as_float((unsigned)(127 - _ex) << 23);                   \
        esum += _ex;                                                        \
      }                                                                     \
      unsigned int W[8], X[8];                                              \
      _Pragma("unroll") for (int q = 0; q < 8; ++q) W[q] =                  \
          cvtpk_bf16(Cl[2 * q] * _s, Cl[2 * q + 1] * _s);                   \
      _Pragma("unroll") for (int q = 0; q < 8; ++q) X[q] =                  \
          __shfl_xor((int)W[q], 32);                                        \
      B0.u[0] = h ? X[2] : W[0];                                            \
      B0.u[1] = h ? X[3] : W[1];                                            \
      B0.u[2] = h ? W[2] : X[0];                                            \
      B0.u[3] = h ? W[3] : X[1];                                            \
      B1.u[0] = h ? X[6] : W[4];                                            \
      B1.u[1] = h ? X[7] : W[5];                                            \
      B1.u[2] = h ? W[6] : X[4];                                            \
      B1.u[3] = h ? W[7] : X[5];                                            \
    } else {                                                                \
      C = Cl;                                                               \
    }                                                                       \
  } while (0)

  float r0[16], r1[16];
  LOADE(r0, 0);
  LOADE(r1, (nsteps > 1) ? 1 : 0);
  int esum = 0;
  fx16 C;
#pragma unroll
  for (int q = 0; q < 16; ++q) C[q] = 0.f;

  int t = 0;
  while (t < nsteps) {
    STEPB(r0);
    ++t;
    if (t >= nsteps) break;
    STEPB(r1);
    ++t;
  }

  // final normalize (max into [1,2)) and store f32 matrix + esum
  float mx = C[0];
#pragma unroll
  for (int q = 1; q < 16; ++q) mx = fmaxf(mx, C[q]);
  mx = fmaxf(mx, __shfl_xor(mx, 32));
  mx = fmaxf(mx, __shfl_xor(mx, 1));
  mx = fmaxf(mx, __shfl_xor(mx, 2));
  mx = fmaxf(mx, __shfl_xor(mx, 4));
  mx = fmaxf(mx, __shfl_xor(mx, 8));
  mx = fmaxf(mx, __shfl_xor(mx, 16));
  int ex = ((__float_as_int(mx) >> 23) & 255) - 127;
  float s = __int_as_float((unsigned)(127 - ex) << 23);
  esum += ex;
#pragma unroll
  for (int r = 0; r < 16; ++r) {
    int row = (r & 3) + 8 * (r >> 2) + 4 * h;
    mout[row * 32 + c] = C[r] * s;
  }
  if (l == 0) mout[1024] = (float)esum;
#undef STEPB
#undef LOADE
}

// ---------------------------------------------------------------------------
// Stage 2: one wave per (batch, direction). dir0: v <- M_seg * v for
// seg = 0..half-1 starting v = ones. dir1: r <- r * M_seg for
// seg = nseg-1 .. half. Every step: exact power-of-2 rescale of the state
// (exponent accumulated into esv) -- at half=16 the unrescaled state would
// overflow f32 (matrices give up to ~2^6 growth/step; 2^96 per side; the
// final dot of two such vectors exceeds 2^127).
__global__ __launch_bounds__(64) void comb_kernel(float* __restrict__ ws,
                                                  int nseg) {
  const int bid = blockIdx.x;
  const int b = bid & (BB - 1);
  const int dir = bid >> 6;
  const int l = threadIdx.x;
  const int lo = l & 31;
  const int h = l >> 5;
  const int half = nseg >> 1;
  __shared__ alignas(16) float st[TT];

#define FENCE() asm volatile("s_waitcnt lgkmcnt(0)" ::: "memory")

  float cur = dir ? ((lo == ENDI) ? 1.0f : 0.0f) : 1.0f;
  st[lo] = cur;
  FENCE();

  const float* segbase = ws + 512;
  float esv = 0.f;

#define LOADM(buf, SEG)                                                     \
  do {                                                                      \
    const float* _m = segbase + (size_t)(b * nseg + (SEG)) * 1056;          \
    if (dir == 0) { /* need M[lo][h16+j]: contiguous */                     \
      const float4* _p = (const float4*)(_m + lo * 32 + h * 16);            \
      float4 _a = _p[0], _b2 = _p[1], _c2 = _p[2], _d = _p[3];              \
      buf[0] = _a.x;  buf[1] = _a.y;  buf[2] = _a.z;  buf[3] = _a.w;        \
      buf[4] = _b2.x; buf[5] = _b2.y; buf[6] = _b2.z; buf[7] = _b2.w;       \
      buf[8] = _c2.x; buf[9] = _c2.y; buf[10] = _c2.z; buf[11] = _c2.w;     \
      buf[12] = _d.x; buf[13] = _d.y; buf[14] = _d.z; buf[15] = _d.w;       \
    } else { /* need M[h16+j][lo]: stride 32 */                             \
      const float* _p = _m + (h * 16) * 32 + lo;                            \
      _Pragma("unroll") for (int _j = 0; _j < 16; ++_j)                     \
          buf[_j] = _p[_j * 32];                                            \
    }                                                                       \
  } while (0)

  float mc[16], mn[16];
#pragma unroll
  for (int q = 0; q < 16; ++q) mn[q] = 0.f;
  {
    int seg0 = dir ? (nseg - 1) : 0;
    LOADM(mc, seg0);
  }
  for (int k = 0; k < half; ++k) {
    int segn = dir ? (nseg - 2 - k) : (k + 1);
    if (k + 1 < half) LOADM(mn, segn);
    int segc = dir ? (nseg - 1 - k) : k;
    esv += segbase[(size_t)(b * nseg + segc) * 1056 + 1024];
    const float4* g4 = (const float4*)st;
    float4 g0 = g4[h * 4 + 0], g1 = g4[h * 4 + 1], g2 = g4[h * 4 + 2],
           g3 = g4[h * 4 + 3];
    float g[16] = {g0.x, g0.y, g0.z, g0.w, g1.x, g1.y, g1.z, g1.w,
                   g2.x, g2.y, g2.z, g2.w, g3.x, g3.y, g3.z, g3.w};
    float acc[4];
#pragma unroll
    for (int q = 0; q < 4; ++q) {
      acc[q] = mc[4 * q] * g[4 * q];
#pragma unroll
      for (int t = 1; t < 4; ++t)
        acc[q] = fmaf(mc[4 * q + t], g[4 * q + t], acc[q]);
    }
    float part = (acc[0] + acc[1]) + (acc[2] + acc[3]);
    cur = part + __shfl_xor(part, 32);
    // exact power-of-2 rescale: max over the 32 state entries (replicated
    // across h), exponent into esv
    float mxv = cur;
    mxv = fmaxf(mxv, __shfl_xor(mxv, 1));
    mxv = fmaxf(mxv, __shfl_xor(mxv, 2));
    mxv = fmaxf(mxv, __shfl_xor(mxv, 4));
    mxv = fmaxf(mxv, __shfl_xor(mxv, 8));
    mxv = fmaxf(mxv, __shfl_xor(mxv, 16));
    int exv = ((__float_as_int(mxv) >> 23) & 255) - 127;
    cur *= __int_as_float((unsigned)(127 - exv) << 23);
    esv += (float)exv;
    FENCE();  // all lanes done reading st before overwrite
    st[lo] = cur;
    FENCE();
#pragma unroll
    for (int q = 0; q < 16; ++q) mc[q] = mn[q];
  }

  float* o = ws + 512 + (size_t)BB * nseg * 1056 + (size_t)(b * 2 + dir) * 40;
  if (h == 0) o[lo] = cur;
  if (l == 0) o[32] = esv;
#undef LOADM
#undef FENCE
}

// ---------------------------------------------------------------------------
// Final: per batch, loss_b = (esumF+esumB)*ln2 + log(dot(vF, rB)); sum over
// batches; subtract summed gold partials.
__global__ __launch_bounds__(64) void fin_kernel(const float* __restrict__ ws,
                                                 int nseg,
                                                 float* __restrict__ out) {
  int b = threadIdx.x;  // 64 lanes = 64 batches
  const float* cb = ws + 512 + (size_t)BB * nseg * 1056;
  const float* vF = cb + (size_t)b * 80;
  const float* rB = vF + 40;
  float dot = 0.f;
#pragma unroll
  for (int j = 0; j < 32; ++j) dot = fmaf(vF[j], rB[j], dot);
  float r = (vF[32] + rB[32]) * 0.6931471805599453f + __logf(dot);
  float gp = 0.f;
#pragma unroll
  for (int j = 0; j < 8; ++j) gp += ws[b * 8 + j];
#pragma unroll
  for (int o = 32; o; o >>= 1) {
    r += __shfl_xor(r, o);
    gp += __shfl_xor(gp, o);
  }
  if (b == 0) out[0] = r - gp;
}

// ---------------------------------------------------------------------------
extern "C" void kernel_launch(void* const* d_in, const int* in_sizes, int n_in,
                              void* d_out, int out_size, void* d_ws,
                              size_t ws_size, hipStream_t stream) {
  const float* scores = (const float*)d_in[0];
  const int* targets = (const int*)d_in[1];
  const int* lengths = (const int*)d_in[2];
  float* out = (float*)d_out;
  float* ws = (float*)d_ws;

  // pick nseg to fit the workspace (gold partials + matrices + combine outs)
  int nseg = 32;
  while (nseg > 2) {
    size_t need =
        (size_t)(512 + BB * nseg * 1056 + BB * 2 * 40) * sizeof(float);
    if (need <= ws_size) break;
    nseg >>= 1;
  }
  int seglen = SS / nseg;

  gold_kernel<<<(BB * SS) / 256, 256, 0, stream>>>(scores, targets, lengths,
                                                   ws);
  seg_kernel<<<dim3(BB, nseg), 64, 0, stream>>>(scores, lengths, ws, nseg,
                                                seglen);
  comb_kernel<<<2 * BB, 64, 0, stream>>>(ws, nseg);
  fin_kernel<<<1, 64, 0, stream>>>(ws, nseg, out);
}

// Round 6
// 51.238 us; speedup vs baseline: 2.4120x; 1.1214x over previous
//
#include <hip/hip_runtime.h>
#include <hip/hip_bf16.h>

#define BB 64
#define SS 512
#define TT 32
#define ENDI 31
#define ACCS 0   // float accumulator for sum_b (loss_b)
#define CNTS 1   // uint completion counter
#define GOLDB 16 // per-task gold partials, BB*nseg slots

typedef __attribute__((ext_vector_type(8))) short s8v;    // 8 bf16 (4 VGPR)
typedef __attribute__((ext_vector_type(16))) float fx16;  // MFMA accumulator

union S8U {
  s8v v;
  unsigned int u[4];
};

__device__ __forceinline__ unsigned int cvtpk_bf16(float a, float b) {
  unsigned int r;
  asm("v_cvt_pk_bf16_f32 %0, %1, %2" : "=v"(r) : "v"(a), "v"(b));
  return r;
}

// ---------------------------------------------------------------------------
// Stage 1: one wave per (batch, segment).
//  (a) gold partial for this segment's timesteps -> ws[GOLDB + task]
//  (b) exp-domain segment product P_seg = E_{hi-1}...E_{lo} (normalized,
//      max in [1,2)) + esum -> matrix region
//  block (0,0) also zeroes the acc/count slots used by stage 2.
// MFMA layouts (v_mfma_f32_32x32x16_bf16), c = lane&31, h = lane>>5:
//   A slot j (chunk q): A[row=c][k = 16q + 8h + j]
//   B slot j (chunk q): B[k = 16q + 8h + j][col=c]
//   D reg r:            D[row = (r&3) + 8*(r>>2) + 4h][col=c]   (HW-verified)
__global__ __launch_bounds__(64) void seg_kernel(
    const float* __restrict__ sc, const int* __restrict__ targets,
    const int* __restrict__ lengths, float* __restrict__ ws, int nseg,
    int seglen) {
  const int b = blockIdx.x;
  const int seg = blockIdx.y;
  const int l = threadIdx.x;
  const int c = l & 31;
  const int h = l >> 5;
  const int len = lengths[b];
  const int lo = seg * seglen;

  if (b == 0 && seg == 0 && l == 0) {
    ws[ACCS] = 0.0f;
    ((unsigned*)ws)[CNTS] = 0u;
  }

  // ---- gold partial for s in [lo, lo+seglen) ----
  {
    float gv = 0.f;
    for (int s0 = l; s0 < seglen; s0 += 64) {
      int s = lo + s0;
      if (s < len) {
        int idx = b * SS + s;
        gv += sc[(size_t)idx * 1024 + (size_t)targets[idx]];
      }
    }
#pragma unroll
    for (int o = 32; o; o >>= 1) gv += __shfl_xor(gv, o);
    if (l == 0) ws[GOLDB + b * nseg + seg] = gv;
  }

  float* mout = ws + GOLDB + BB * nseg + (size_t)(b * nseg + seg) * 1056;

  if (len <= lo) {  // segment fully past the sequence: identity
#pragma unroll
    for (int r = 0; r < 16; ++r) {
      int row = (r & 3) + 8 * (r >> 2) + 4 * h;
      mout[row * 32 + c] = (row == c) ? 1.0f : 0.0f;
    }
    if (l == 0) mout[1024] = 0.0f;
    return;
  }

  const int hi = (lo + seglen < len) ? (lo + seglen) : len;
  const int nsteps = hi - lo;
  const float* base = sc + ((size_t)b * SS + lo) * 1024;

  // B state = identity (bf16 1.0 = 0x3F80 at m == c)
  S8U B0, B1;
#pragma unroll
  for (int q = 0; q < 4; ++q) {
    B0.u[q] = 0u;
    B1.u[q] = 0u;
  }
  {
    int j0 = c - 8 * h;  // chunk0 holds m = 8h+j
    if (j0 >= 0 && j0 < 8) B0.u[j0 >> 1] |= 0x3F80u << (16 * (j0 & 1));
    int j1 = c - 16 - 8 * h;  // chunk1 holds m = 16+8h+j
    if (j1 >= 0 && j1 < 8) B1.u[j1 >> 1] |= 0x3F80u << (16 * (j1 & 1));
  }

// Load E-row raw scores for step T: lane (c,h) takes cols [8h,8h+8) and
// [16+8h,16+8h+8) of row c.
#define LOADE(buf, T)                                                     \
  do {                                                                    \
    const float* _p = base + (size_t)(T) * 1024 + c * 32 + 8 * h;         \
    float4 _a = *(const float4*)_p;                                       \
    float4 _b = *(const float4*)(_p + 4);                                 \
    float4 _c = *(const float4*)(_p + 16);                                \
    float4 _d = *(const float4*)(_p + 20);                                \
    buf[0] = _a.x;  buf[1] = _a.y;  buf[2] = _a.z;  buf[3] = _a.w;        \
    buf[4] = _b.x;  buf[5] = _b.y;  buf[6] = _b.z;  buf[7] = _b.w;        \
    buf[8] = _c.x;  buf[9] = _c.y;  buf[10] = _c.z; buf[11] = _c.w;       \
    buf[12] = _d.x; buf[13] = _d.y; buf[14] = _d.z; buf[15] = _d.w;       \
  } while (0)

// One chain step consuming raw buffer RB; re-issues RB's load for step t+3
// (clamped; duplicate loads of an already-valid row are harmless).
#define STEPB(RB)                                                            \
  do {                                                                      \
    S8U A0, A1;                                                             \
    _Pragma("unroll") for (int q = 0; q < 4; ++q) {                         \
      A0.u[q] = cvtpk_bf16(__expf(RB[2 * q]), __expf(RB[2 * q + 1]));       \
      A1.u[q] = cvtpk_bf16(__expf(RB[8 + 2 * q]), __expf(RB[9 + 2 * q]));   \
    }                                                                       \
    int _pf = t + 3;                                                        \
    if (_pf >= nsteps) _pf = nsteps - 1;                                    \
    LOADE(RB, _pf);                                                         \
    fx16 Cl;                                                                \
    _Pragma("unroll") for (int q = 0; q < 16; ++q) Cl[q] = 0.f;             \
    Cl = __builtin_amdgcn_mfma_f32_32x32x16_bf16(A0.v, B0.v, Cl, 0, 0, 0);  \
    Cl = __builtin_amdgcn_mfma_f32_32x32x16_bf16(A1.v, B1.v, Cl, 0, 0, 0);  \
    if (t + 1 < nsteps) {                                                   \
      float _s = 1.0f;                                                      \
      if ((t & 3) == 3) { /* wave-uniform power-of-2 rescale */             \
        float _mx = Cl[0];                                                  \
        _Pragma("unroll") for (int q = 1; q < 16; ++q) _mx =                \
            fmaxf(_mx, Cl[q]);                                              \
        _mx = fmaxf(_mx, __shfl_xor(_mx, 32));                              \
        _mx = fmaxf(_mx, __shfl_xor(_mx, 1));                               \
        _mx = fmaxf(_mx, __shfl_xor(_mx, 2));                               \
        _mx = fmaxf(_mx, __shfl_xor(_mx, 4));                               \
        _mx = fmaxf(_mx, __shfl_xor(_mx, 8));                               \
        _mx = fmaxf(_mx, __shfl_xor(_mx, 16));                              \
        int _ex = ((__float_as_int(_mx) >> 23) & 255) - 127;                \
        _s = __int_as_float((unsigned)(127 - _ex) << 23);                   \
        esum += _ex;                                                        \
      }                                                                     \
      unsigned int W[8], X[8];                                              \
      _Pragma("unroll") for (int q = 0; q < 8; ++q) W[q] =                  \
          cvtpk_bf16(Cl[2 * q] * _s, Cl[2 * q + 1] * _s);                   \
      _Pragma("unroll") for (int q = 0; q < 8; ++q) X[q] =                  \
          __shfl_xor((int)W[q], 32);                                        \
      B0.u[0] = h ? X[2] : W[0];                                            \
      B0.u[1] = h ? X[3] : W[1];                                            \
      B0.u[2] = h ? W[2] : X[0];                                            \
      B0.u[3] = h ? W[3] : X[1];                                            \
      B1.u[0] = h ? X[6] : W[4];                                            \
      B1.u[1] = h ? X[7] : W[5];                                            \
      B1.u[2] = h ? W[6] : X[4];                                            \
      B1.u[3] = h ? W[7] : X[5];                                            \
    } else {                                                                \
      C = Cl;                                                               \
    }                                                                       \
  } while (0)

  float r0[16], r1[16], r2[16];
  LOADE(r0, 0);
  LOADE(r1, (nsteps > 1) ? 1 : 0);
  LOADE(r2, (nsteps > 2) ? 2 : 0);
  int esum = 0;
  fx16 C;
#pragma unroll
  for (int q = 0; q < 16; ++q) C[q] = 0.f;

  int t = 0;
  while (t < nsteps) {
    STEPB(r0);
    ++t;
    if (t >= nsteps) break;
    STEPB(r1);
    ++t;
    if (t >= nsteps) break;
    STEPB(r2);
    ++t;
  }

  // final normalize (max into [1,2)) and store f32 matrix + esum
  float mx = C[0];
#pragma unroll
  for (int q = 1; q < 16; ++q) mx = fmaxf(mx, C[q]);
  mx = fmaxf(mx, __shfl_xor(mx, 32));
  mx = fmaxf(mx, __shfl_xor(mx, 1));
  mx = fmaxf(mx, __shfl_xor(mx, 2));
  mx = fmaxf(mx, __shfl_xor(mx, 4));
  mx = fmaxf(mx, __shfl_xor(mx, 8));
  mx = fmaxf(mx, __shfl_xor(mx, 16));
  int ex = ((__float_as_int(mx) >> 23) & 255) - 127;
  float s = __int_as_float((unsigned)(127 - ex) << 23);
  esum += ex;
#pragma unroll
  for (int r = 0; r < 16; ++r) {
    int row = (r & 3) + 8 * (r >> 2) + 4 * h;
    mout[row * 32 + c] = C[r] * s;
  }
  if (l == 0) mout[1024] = (float)esum;
#undef STEPB
#undef LOADE
}

// ---------------------------------------------------------------------------
// Stage 2: one block per batch, 2 waves (wave w = direction).
//  w0: v <- M_seg * v, seg = 0..half-1, v0 = ones
//  w1: r <- r * M_seg, seg = nseg-1..half, r0 = e_END
// Power-of-2 rescale every 4th step (growth <= 2^25 between rescales, safe).
// Then block-combine: loss_b = (esvF+esvB)*ln2 + log(dot(vF,rB)) - gold_b,
// atomicAdd into ws[ACCS]; last block (completion counter) writes out[0].
__global__ __launch_bounds__(128) void comb_fin_kernel(
    float* __restrict__ ws, int nseg, float* __restrict__ out) {
  const int b = blockIdx.x;
  const int w = threadIdx.x >> 6;  // direction
  const int l = threadIdx.x & 63;
  const int lo = l & 31;
  const int h = l >> 5;
  const int half = nseg >> 1;
  __shared__ alignas(16) float st[2][TT];
  __shared__ float esvS[2];

#define FENCE() asm volatile("s_waitcnt lgkmcnt(0)" ::: "memory")

  float cur = w ? ((lo == ENDI) ? 1.0f : 0.0f) : 1.0f;
  st[w][lo] = cur;
  FENCE();

  const float* segbase = ws + GOLDB + BB * nseg;
  float esv = 0.f;

#define LOADM(buf, SEG)                                                     \
  do {                                                                      \
    const float* _m = segbase + (size_t)(b * nseg + (SEG)) * 1056;          \
    if (w == 0) { /* need M[lo][h16+j]: contiguous */                       \
      const float4* _p = (const float4*)(_m + lo * 32 + h * 16);            \
      float4 _a = _p[0], _b2 = _p[1], _c2 = _p[2], _d = _p[3];              \
      buf[0] = _a.x;  buf[1] = _a.y;  buf[2] = _a.z;  buf[3] = _a.w;        \
      buf[4] = _b2.x; buf[5] = _b2.y; buf[6] = _b2.z; buf[7] = _b2.w;       \
      buf[8] = _c2.x; buf[9] = _c2.y; buf[10] = _c2.z; buf[11] = _c2.w;     \
      buf[12] = _d.x; buf[13] = _d.y; buf[14] = _d.z; buf[15] = _d.w;       \
    } else { /* need M[h16+j][lo]: stride 32 */                             \
      const float* _p = _m + (h * 16) * 32 + lo;                            \
      _Pragma("unroll") for (int _j = 0; _j < 16; ++_j)                     \
          buf[_j] = _p[_j * 32];                                            \
    }                                                                       \
  } while (0)

  float mc[16], mn[16];
#pragma unroll
  for (int q = 0; q < 16; ++q) mn[q] = 0.f;
  {
    int seg0 = w ? (nseg - 1) : 0;
    LOADM(mc, seg0);
  }
  for (int k = 0; k < half; ++k) {
    int segn = w ? (nseg - 2 - k) : (k + 1);
    if (k + 1 < half) LOADM(mn, segn);
    int segc = w ? (nseg - 1 - k) : k;
    esv += segbase[(size_t)(b * nseg + segc) * 1056 + 1024];
    const float4* g4 = (const float4*)st[w];
    float4 g0 = g4[h * 4 + 0], g1 = g4[h * 4 + 1], g2 = g4[h * 4 + 2],
           g3 = g4[h * 4 + 3];
    float g[16] = {g0.x, g0.y, g0.z, g0.w, g1.x, g1.y, g1.z, g1.w,
                   g2.x, g2.y, g2.z, g2.w, g3.x, g3.y, g3.z, g3.w};
    float acc[4];
#pragma unroll
    for (int q = 0; q < 4; ++q) {
      acc[q] = mc[4 * q] * g[4 * q];
#pragma unroll
      for (int t = 1; t < 4; ++t)
        acc[q] = fmaf(mc[4 * q + t], g[4 * q + t], acc[q]);
    }
    float part = (acc[0] + acc[1]) + (acc[2] + acc[3]);
    cur = part + __shfl_xor(part, 32);
    if ((k & 3) == 3) {  // power-of-2 rescale (max growth 2^25 between)
      float mxv = cur;
      mxv = fmaxf(mxv, __shfl_xor(mxv, 1));
      mxv = fmaxf(mxv, __shfl_xor(mxv, 2));
      mxv = fmaxf(mxv, __shfl_xor(mxv, 4));
      mxv = fmaxf(mxv, __shfl_xor(mxv, 8));
      mxv = fmaxf(mxv, __shfl_xor(mxv, 16));
      int exv = ((__float_as_int(mxv) >> 23) & 255) - 127;
      cur *= __int_as_float((unsigned)(127 - exv) << 23);
      esv += (float)exv;
    }
    FENCE();  // own wave's prior LDS reads done before overwrite
    st[w][lo] = cur;
    FENCE();
#pragma unroll
    for (int q = 0; q < 16; ++q) mc[q] = mn[q];
  }

  if (l == 0) esvS[w] = esv;
  __syncthreads();

  if (w == 0) {
    // dot(vF, rB) over 32 entries + gold partial sum, lanes 0..31 (h copies
    // redundant but harmless; reductions confined to xor<32)
    float pr = st[0][lo] * st[1][lo];
    float gd = (lo < nseg) ? ws[GOLDB + b * nseg + lo] : 0.f;
#pragma unroll
    for (int o = 16; o; o >>= 1) {
      pr += __shfl_xor(pr, o);
      gd += __shfl_xor(gd, o);
    }
    if (l == 0) {
      float loss =
          (esvS[0] + esvS[1]) * 0.6931471805599453f + __logf(pr) - gd;
      atomicAdd(&ws[ACCS], loss);
      __threadfence();
      unsigned old = atomicAdd(&((unsigned*)ws)[CNTS], 1u);
      if (old == BB - 1) {  // last block: publish
        float v = atomicAdd(&ws[ACCS], 0.0f);
        out[0] = v;
      }
    }
  }
#undef LOADM
#undef FENCE
}

// ---------------------------------------------------------------------------
extern "C" void kernel_launch(void* const* d_in, const int* in_sizes, int n_in,
                              void* d_out, int out_size, void* d_ws,
                              size_t ws_size, hipStream_t stream) {
  const float* scores = (const float*)d_in[0];
  const int* targets = (const int*)d_in[1];
  const int* lengths = (const int*)d_in[2];
  float* out = (float*)d_out;
  float* ws = (float*)d_ws;

  // pick nseg to fit the workspace (acc/count + gold partials + matrices)
  int nseg = 32;
  while (nseg > 2) {
    size_t need =
        (size_t)(GOLDB + BB * nseg + (size_t)BB * nseg * 1056) * sizeof(float);
    if (need <= ws_size) break;
    nseg >>= 1;
  }
  int seglen = SS / nseg;

  seg_kernel<<<dim3(BB, nseg), 64, 0, stream>>>(scores, targets, lengths, ws,
                                                nseg, seglen);
  comb_fin_kernel<<<BB, 128, 0, stream>>>(ws, nseg, out);
}

// Round 8
// 49.786 us; speedup vs baseline: 2.4823x; 1.0292x over previous
//
#include <hip/hip_runtime.h>
#include <hip/hip_bf16.h>

#define BB 64
#define SS 512
#define TT 32
#define ENDI 31
#define NSEG 32
#define SEGLEN 16
#define ACCS 0   // float accumulator for sum_b (loss_b)
#define CNTS 1   // uint completion counter
#define GOLDB 16 // per-task gold partials, BB*NSEG slots

typedef __attribute__((ext_vector_type(8))) short s8v;    // 8 bf16 (4 VGPR)
typedef __attribute__((ext_vector_type(16))) float fx16;  // MFMA accumulator

union S8U {
  s8v v;
  unsigned int u[4];
};

__device__ __forceinline__ unsigned int cvtpk_bf16(float a, float b) {
  unsigned int r;
  asm("v_cvt_pk_bf16_f32 %0, %1, %2" : "=v"(r) : "v"(a), "v"(b));
  return r;
}

// ---------------------------------------------------------------------------
// Stage 1: one wave per (batch, segment). Exp-domain segment product
// P_seg = E_{hi-1}...E_{lo} (E_s = exp(scores[b,s])) as a normalized 32x32
// f32 matrix (max in [1,2)) + esum. Full segments (nsteps==16) use a chunked
// load/compute pipeline; partial segments use the R6-proven serial loop.
//
// MFMA layouts (v_mfma_f32_32x32x16_bf16), c = lane&31, h = lane>>5:
//   A slot j (chunk q): A[row=c][k = 16q + 8h + j]
//   B slot j (chunk q): B[k = 16q + 8h + j][col=c]
//   D reg r:            D[row = (r&3) + 8*(r>>2) + 4h][col=c]   (HW-verified)
__global__ __launch_bounds__(64) void seg_kernel(
    const float* __restrict__ sc, const int* __restrict__ targets,
    const int* __restrict__ lengths, float* __restrict__ ws) {
  const int b = blockIdx.x;
  const int seg = blockIdx.y;
  const int l = threadIdx.x;
  const int c = l & 31;
  const int h = l >> 5;
  const int len = lengths[b];
  const int lo = seg * SEGLEN;

  if (b == 0 && seg == 0 && l == 0) {
    ws[ACCS] = 0.0f;
    ((unsigned*)ws)[CNTS] = 0u;
  }

  // ---- gold partial for s in [lo, lo+SEGLEN) ----
  {
    float gv = 0.f;
    if (l < SEGLEN) {
      int s = lo + l;
      if (s < len) {
        int idx = b * SS + s;
        gv = sc[(size_t)idx * 1024 + (size_t)targets[idx]];
      }
    }
#pragma unroll
    for (int o = 32; o; o >>= 1) gv += __shfl_xor(gv, o);
    if (l == 0) ws[GOLDB + b * NSEG + seg] = gv;
  }

  float* mout = ws + GOLDB + BB * NSEG + (size_t)(b * NSEG + seg) * 1056;

  if (len <= lo) {  // segment fully past the sequence: identity matrix
#pragma unroll
    for (int r = 0; r < 16; ++r) {
      int row = (r & 3) + 8 * (r >> 2) + 4 * h;
      mout[row * 32 + c] = (row == c) ? 1.0f : 0.0f;
    }
    if (l == 0) mout[1024] = 0.0f;
    return;
  }

  const int nsteps = (len - lo < SEGLEN) ? (len - lo) : SEGLEN;
  const float* base = sc + ((size_t)b * SS + lo) * 1024;

  // B state = identity (bf16 1.0 = 0x3F80 at m == c)
  S8U B0, B1;
#pragma unroll
  for (int q = 0; q < 4; ++q) {
    B0.u[q] = 0u;
    B1.u[q] = 0u;
  }
  {
    int j0 = c - 8 * h;  // chunk0 holds m = 8h+j
    if (j0 >= 0 && j0 < 8) B0.u[j0 >> 1] |= 0x3F80u << (16 * (j0 & 1));
    int j1 = c - 16 - 8 * h;  // chunk1 holds m = 16+8h+j
    if (j1 >= 0 && j1 < 8) B1.u[j1 >> 1] |= 0x3F80u << (16 * (j1 & 1));
  }

// Load E-row raw scores for step T: lane (c,h) takes cols [8h,8h+8) and
// [16+8h,16+8h+8) of row c.
#define LOADE(buf, T)                                                     \
  do {                                                                    \
    const float* _p = base + (size_t)(T) * 1024 + c * 32 + 8 * h;         \
    float4 _a = *(const float4*)_p;                                       \
    float4 _b = *(const float4*)(_p + 4);                                 \
    float4 _c = *(const float4*)(_p + 16);                                \
    float4 _d = *(const float4*)(_p + 20);                                \
    buf[0] = _a.x;  buf[1] = _a.y;  buf[2] = _a.z;  buf[3] = _a.w;        \
    buf[4] = _b.x;  buf[5] = _b.y;  buf[6] = _b.z;  buf[7] = _b.w;        \
    buf[8] = _c.x;  buf[9] = _c.y;  buf[10] = _c.z; buf[11] = _c.w;       \
    buf[12] = _d.x; buf[13] = _d.y; buf[14] = _d.z; buf[15] = _d.w;       \
  } while (0)

// Rescale Cl by a wave-uniform power of 2 (exponent into esum)
#define RESCALE(SVAR)                                                     \
  do {                                                                    \
    float _mx = Cl[0];                                                    \
    _Pragma("unroll") for (int q = 1; q < 16; ++q) _mx = fmaxf(_mx, Cl[q]); \
    _mx = fmaxf(_mx, __shfl_xor(_mx, 32));                                \
    _mx = fmaxf(_mx, __shfl_xor(_mx, 1));                                 \
    _mx = fmaxf(_mx, __shfl_xor(_mx, 2));                                 \
    _mx = fmaxf(_mx, __shfl_xor(_mx, 4));                                 \
    _mx = fmaxf(_mx, __shfl_xor(_mx, 8));                                 \
    _mx = fmaxf(_mx, __shfl_xor(_mx, 16));                                \
    int _ex = ((__float_as_int(_mx) >> 23) & 255) - 127;                  \
    SVAR = __int_as_float((unsigned)(127 - _ex) << 23);                   \
    esum += _ex;                                                          \
  } while (0)

// Repack D (Cl, scaled by s) into the B operand for the next step
#define REPACK()                                                          \
  do {                                                                    \
    unsigned int W[8], X[8];                                              \
    _Pragma("unroll") for (int q = 0; q < 8; ++q) W[q] =                  \
        cvtpk_bf16(Cl[2 * q] * s, Cl[2 * q + 1] * s);                     \
    _Pragma("unroll") for (int q = 0; q < 8; ++q) X[q] =                  \
        __shfl_xor((int)W[q], 32);                                        \
    B0.u[0] = h ? X[2] : W[0];                                            \
    B0.u[1] = h ? X[3] : W[1];                                            \
    B0.u[2] = h ? W[2] : X[0];                                            \
    B0.u[3] = h ? W[3] : X[1];                                            \
    B1.u[0] = h ? X[6] : W[4];                                            \
    B1.u[1] = h ? X[7] : W[5];                                            \
    B1.u[2] = h ? W[6] : X[4];                                            \
    B1.u[3] = h ? W[7] : X[5];                                            \
  } while (0)

  int esum = 0;
  fx16 C;
#pragma unroll
  for (int q = 0; q < 16; ++q) C[q] = 0.f;

  if (nsteps == SEGLEN) {
    // ---- full segment: chunked pipeline, all 16 steps real ----
    float L[4][16];
    S8U A4[4][2];
#pragma unroll
    for (int j = 0; j < 4; ++j) LOADE(L[j], j);

#pragma unroll
    for (int ch = 0; ch < 4; ++ch) {
      // convert landing -> exp'd bf16 A operands (off the MFMA chain)
#pragma unroll
      for (int k = 0; k < 4; ++k) {
#pragma unroll
        for (int q = 0; q < 4; ++q) {
          A4[k][0].u[q] =
              cvtpk_bf16(__expf(L[k][2 * q]), __expf(L[k][2 * q + 1]));
          A4[k][1].u[q] =
              cvtpk_bf16(__expf(L[k][8 + 2 * q]), __expf(L[k][9 + 2 * q]));
        }
      }
      // issue next chunk's loads; they stay in flight through the MFMAs
      if (ch < 3) {
#pragma unroll
        for (int j = 0; j < 4; ++j) LOADE(L[j], (ch + 1) * 4 + j);
      }
      // 4 MFMA steps; only the D->B repack is on the critical path
#pragma unroll
      for (int k = 0; k < 4; ++k) {
        fx16 Cl;
#pragma unroll
        for (int q = 0; q < 16; ++q) Cl[q] = 0.f;
        Cl = __builtin_amdgcn_mfma_f32_32x32x16_bf16(A4[k][0].v, B0.v, Cl,
                                                     0, 0, 0);
        Cl = __builtin_amdgcn_mfma_f32_32x32x16_bf16(A4[k][1].v, B1.v, Cl,
                                                     0, 0, 0);
        if (ch == 3 && k == 3) {
          C = Cl;
        } else {
          float s = 1.0f;
          if (k == 3) RESCALE(s);
          REPACK();
        }
      }
    }
  } else {
    // ---- partial segment (<=1 per batch): R6-proven serial loop ----
    float r0[16], r1[16], r2[16];
    LOADE(r0, 0);
    LOADE(r1, (nsteps > 1) ? 1 : 0);
    LOADE(r2, (nsteps > 2) ? 2 : 0);

#define STEPB(RB)                                                            \
    do {                                                                    \
      S8U A0, A1;                                                           \
      _Pragma("unroll") for (int q = 0; q < 4; ++q) {                       \
        A0.u[q] = cvtpk_bf16(__expf(RB[2 * q]), __expf(RB[2 * q + 1]));     \
        A1.u[q] = cvtpk_bf16(__expf(RB[8 + 2 * q]), __expf(RB[9 + 2 * q])); \
      }                                                                     \
      int _pf = t + 3;                                                      \
      if (_pf >= nsteps) _pf = nsteps - 1;                                  \
      LOADE(RB, _pf);                                                       \
      fx16 Cl;                                                              \
      _Pragma("unroll") for (int q = 0; q < 16; ++q) Cl[q] = 0.f;           \
      Cl = __builtin_amdgcn_mfma_f32_32x32x16_bf16(A0.v, B0.v, Cl, 0, 0, 0);\
      Cl = __builtin_amdgcn_mfma_f32_32x32x16_bf16(A1.v, B1.v, Cl, 0, 0, 0);\
      if (t + 1 < nsteps) {                                                 \
        float s = 1.0f;                                                     \
        if ((t & 3) == 3) RESCALE(s);                                       \
        REPACK();                                                           \
      } else {                                                              \
        C = Cl;                                                             \
      }                                                                     \
    } while (0)

    int t = 0;
    while (t < nsteps) {
      STEPB(r0);
      ++t;
      if (t >= nsteps) break;
      STEPB(r1);
      ++t;
      if (t >= nsteps) break;
      STEPB(r2);
      ++t;
    }
#undef STEPB
  }

  // final normalize (max into [1,2)) and store f32 matrix + esum
  float mx = C[0];
#pragma unroll
  for (int q = 1; q < 16; ++q) mx = fmaxf(mx, C[q]);
  mx = fmaxf(mx, __shfl_xor(mx, 32));
  mx = fmaxf(mx, __shfl_xor(mx, 1));
  mx = fmaxf(mx, __shfl_xor(mx, 2));
  mx = fmaxf(mx, __shfl_xor(mx, 4));
  mx = fmaxf(mx, __shfl_xor(mx, 8));
  mx = fmaxf(mx, __shfl_xor(mx, 16));
  int ex = ((__float_as_int(mx) >> 23) & 255) - 127;
  float s = __int_as_float((unsigned)(127 - ex) << 23);
  esum += ex;
#pragma unroll
  for (int r = 0; r < 16; ++r) {
    int row = (r & 3) + 8 * (r >> 2) + 4 * h;
    mout[row * 32 + c] = C[r] * s;
  }
  if (l == 0) mout[1024] = (float)esum;
#undef REPACK
#undef RESCALE
#undef LOADE
}

// ---------------------------------------------------------------------------
// Stage 2: one block per batch, 2 waves (wave w = direction).
//  w0: v <- M_seg * v, seg = 0..15, v0 = ones
//  w1: r <- r * M_seg, seg = 31..16, r0 = e_END
// Power-of-2 rescale every 4th step (growth <= 2^25 between rescales, safe).
// Block-combine: loss_b = (esvF+esvB)*ln2 + log(dot(vF,rB)) - gold_b,
// atomicAdd into ws[ACCS]; last block (completion counter) writes out[0].
__global__ __launch_bounds__(128) void comb_fin_kernel(
    float* __restrict__ ws, float* __restrict__ out) {
  const int b = blockIdx.x;
  const int w = threadIdx.x >> 6;  // direction
  const int l = threadIdx.x & 63;
  const int lo = l & 31;
  const int h = l >> 5;
  const int half = NSEG >> 1;
  __shared__ alignas(16) float st[2][TT];
  __shared__ float esvS[2];

#define FENCE() asm volatile("s_waitcnt lgkmcnt(0)" ::: "memory")

  float cur = w ? ((lo == ENDI) ? 1.0f : 0.0f) : 1.0f;
  st[w][lo] = cur;
  FENCE();

  const float* segbase = ws + GOLDB + BB * NSEG;
  float esv = 0.f;

#define LOADM(buf, SEG)                                                     \
  do {                                                                      \
    const float* _m = segbase + (size_t)(b * NSEG + (SEG)) * 1056;          \
    if (w == 0) { /* need M[lo][h16+j]: contiguous */                       \
      const float4* _p = (const float4*)(_m + lo * 32 + h * 16);            \
      float4 _a = _p[0], _b2 = _p[1], _c2 = _p[2], _d = _p[3];              \
      buf[0] = _a.x;  buf[1] = _a.y;  buf[2] = _a.z;  buf[3] = _a.w;        \
      buf[4] = _b2.x; buf[5] = _b2.y; buf[6] = _b2.z; buf[7] = _b2.w;       \
      buf[8] = _c2.x; buf[9] = _c2.y; buf[10] = _c2.z; buf[11] = _c2.w;     \
      buf[12] = _d.x; buf[13] = _d.y; buf[14] = _d.z; buf[15] = _d.w;       \
    } else { /* need M[h16+j][lo]: stride 32, coalesced across lanes */     \
      const float* _p = _m + (h * 16) * 32 + lo;                            \
      _Pragma("unroll") for (int _j = 0; _j < 16; ++_j)                     \
          buf[_j] = _p[_j * 32];                                            \
    }                                                                       \
  } while (0)

  float mc[16], mn[16];
#pragma unroll
  for (int q = 0; q < 16; ++q) mn[q] = 0.f;
  {
    int seg0 = w ? (NSEG - 1) : 0;
    LOADM(mc, seg0);
  }
  for (int k = 0; k < half; ++k) {
    int segn = w ? (NSEG - 2 - k) : (k + 1);
    if (k + 1 < half) LOADM(mn, segn);
    int segc = w ? (NSEG - 1 - k) : k;
    esv += segbase[(size_t)(b * NSEG + segc) * 1056 + 1024];
    const float4* g4 = (const float4*)st[w];
    float4 g0 = g4[h * 4 + 0], g1 = g4[h * 4 + 1], g2 = g4[h * 4 + 2],
           g3 = g4[h * 4 + 3];
    float g[16] = {g0.x, g0.y, g0.z, g0.w, g1.x, g1.y, g1.z, g1.w,
                   g2.x, g2.y, g2.z, g2.w, g3.x, g3.y, g3.z, g3.w};
    float acc[4];
#pragma unroll
    for (int q = 0; q < 4; ++q) {
      acc[q] = mc[4 * q] * g[4 * q];
#pragma unroll
      for (int t = 1; t < 4; ++t)
        acc[q] = fmaf(mc[4 * q + t], g[4 * q + t], acc[q]);
    }
    float part = (acc[0] + acc[1]) + (acc[2] + acc[3]);
    cur = part + __shfl_xor(part, 32);
    if ((k & 3) == 3) {  // power-of-2 rescale (max growth 2^25 between)
      float mxv = cur;
      mxv = fmaxf(mxv, __shfl_xor(mxv, 1));
      mxv = fmaxf(mxv, __shfl_xor(mxv, 2));
      mxv = fmaxf(mxv, __shfl_xor(mxv, 4));
      mxv = fmaxf(mxv, __shfl_xor(mxv, 8));
      mxv = fmaxf(mxv, __shfl_xor(mxv, 16));
      int exv = ((__float_as_int(mxv) >> 23) & 255) - 127;
      cur *= __int_as_float((unsigned)(127 - exv) << 23);
      esv += (float)exv;
    }
    FENCE();  // own wave's prior LDS reads done before overwrite
    st[w][lo] = cur;
    FENCE();
#pragma unroll
    for (int q = 0; q < 16; ++q) mc[q] = mn[q];
  }

  if (l == 0) esvS[w] = esv;
  __syncthreads();

  if (w == 0) {
    float pr = st[0][lo] * st[1][lo];
    float gd = ws[GOLDB + b * NSEG + lo];
#pragma unroll
    for (int o = 16; o; o >>= 1) {
      pr += __shfl_xor(pr, o);
      gd += __shfl_xor(gd, o);
    }
    if (l == 0) {
      float loss =
          (esvS[0] + esvS[1]) * 0.6931471805599453f + __logf(pr) - gd;
      atomicAdd(&ws[ACCS], loss);
      __threadfence();
      unsigned old = atomicAdd(&((unsigned*)ws)[CNTS], 1u);
      if (old == BB - 1) {  // last block: publish
        float v = atomicAdd(&ws[ACCS], 0.0f);
        out[0] = v;
      }
    }
  }
#undef LOADM
#undef FENCE
}

// ---------------------------------------------------------------------------
extern "C" void kernel_launch(void* const* d_in, const int* in_sizes, int n_in,
                              void* d_out, int out_size, void* d_ws,
                              size_t ws_size, hipStream_t stream) {
  const float* scores = (const float*)d_in[0];
  const int* targets = (const int*)d_in[1];
  const int* lengths = (const int*)d_in[2];
  float* out = (float*)d_out;
  float* ws = (float*)d_ws;

  seg_kernel<<<dim3(BB, NSEG), 64, 0, stream>>>(scores, targets, lengths, ws);
  comb_fin_kernel<<<BB, 128, 0, stream>>>(ws, out);
}